// Round 14
// baseline (144.003 us; speedup 1.0000x reference)
//
#include <hip/hip_runtime.h>
#include <type_traits>

#define RES_ 0.16f
#define XMIN_ -51.2f
#define YMIN_ -51.2f
#define EPS_ 1e-5f
#define NEG_ -1000000000.0f

#define WPB 4  // waves per block

typedef _Float16 f16x8 __attribute__((ext_vector_type(8)));
typedef _Float16 f16x4 __attribute__((ext_vector_type(4)));
typedef _Float16 f16x2 __attribute__((ext_vector_type(2)));
typedef float f32x4 __attribute__((ext_vector_type(4)));

union F8u { f16x8 v; f16x2 h[4]; };
union F4u { f16x4 v; f16x2 h[2]; };

// cvt_pkrtz returns __fp16x2 on this clang; launder to _Float16x2 (same bits)
static __device__ __forceinline__ f16x2 pkrtz(float a, float b) {
    return __builtin_bit_cast(f16x2, __builtin_amdgcn_cvt_pkrtz(a, b));
}

static __device__ __forceinline__ f16x2 pmax2(f16x2 a, f16x2 b) {
#if __has_builtin(__builtin_elementwise_max)
    return __builtin_elementwise_max(a, b);    // v_pk_max_f16
#else
    f16x2 r;
    r[0] = a[0] > b[0] ? a[0] : b[0];
    r[1] = a[1] > b[1] ? a[1] : b[1];
    return r;
#endif
}

static __device__ __forceinline__ f16x2 relu2(f16x2 x) {
    const f16x2 z2 = (f16x2)(_Float16)0.f;
    return pmax2(x, z2);
}

static __device__ __forceinline__ float fast_rcp(float x) {
#if __has_builtin(__builtin_amdgcn_rcpf)
    return __builtin_amdgcn_rcpf(x);   // v_rcp_f32, ~1ulp — fine at f16 downstream
#else
    return 1.0f / x;
#endif
}

// r22: single-instruction 3-input max (VOP3; gfx9+). clang does not reliably
// fuse nested fmaxf into v_max3_f32, so force it. Pure, no volatile.
static __device__ __forceinline__ float max3f(float a, float b, float c) {
    float d;
    asm("v_max3_f32 %0, %1, %2, %3" : "=v"(d) : "v"(a), "v"(b), "v"(c));
    return d;
}

// NOTE (r11): zero-LDS dataflow — layer-1 computed transposed (W1^T @ feat^T) so
// its MFMA C-output IS layer-2's A-operand under a W2 k-row permutation
// c(kt,quad,j)=32kt+16(j>>2)+4quad+(j&3). No LDS staging, no h1 round-trip.
// NOTE (ledger, per-dispatch us): r25 = 49.5 (BEST) | r22 = 53.0 (x2) | r13 =
//  57.5 | r16/r23 = 59 | r19 = 60 | r15 = 66 | r21 = 72.5 | r18 = 74 |
//  r14 spill = 252 | r24 init-elision = FAILED (PIN: keep accumulator init).
// NOTE (model): ISSUE/LATENCY EQUILIBRIUM — no pipe near ceiling (VALU 47%,
//  MFMA 21%, HBM 14%); TLP neutral (r15/r19), manual ILP negative (r18/r21),
//  op-diet pays (r22 -7%, r25 -6.6%: issue slots + serial-shfl-chain halving).
// NOTE (attribution): max3f+pointer-bump -4.2us; packed-f16 epilogue -3.5us;
//  shfl beats DPP/permlane (x2). absmax 47.3 tracks max3f reorder — benign,
//  threshold 2e7.
// NOTE (r26, this round — LAST identified diet): cab hoisted out of t-loop
//  (per-pillar), xc/yc as explicit fma, zreduce divide-guard dropped (np=0
//  NaN provably unconsumed: body skipped, res=NEG_). ~5 ops/pillar. If flat,
//  equilibrium is declared.
// Tripwires: WRITE_SIZE==25000KB, VGPR<=60, LDS==0.
__global__ __launch_bounds__(256, 4) void pfn_kernel(
    const float* __restrict__ pillars,
    const int* __restrict__ coords,
    const int* __restrict__ npts_arr,
    const float* __restrict__ W1, const float* __restrict__ b1,
    const float* __restrict__ g1, const float* __restrict__ beta1,
    const float* __restrict__ m1, const float* __restrict__ v1,
    const float* __restrict__ W2, const float* __restrict__ b2,
    const float* __restrict__ g2, const float* __restrict__ beta2,
    const float* __restrict__ m2, const float* __restrict__ v2,
    float* __restrict__ out, int P)
{
    const int tid  = threadIdx.x;
    const int wave = tid >> 6;
    const int lane = tid & 63;
    const int quad = lane >> 4;
    const int col  = lane & 15;

    // ---- W1^T as layer-1 A-frags (K padded 9->16), BN1 scale+bias+z folded ----
    // A[m = mtile*16+col (channel)][k = quad*4+j (feat slot)]
    // slots: {x,y,z,r,xo,yo,z,xo,yo, 1.0(bias), -z_mean(w6 again), 0...}
    f16x4 aw1[4];
#pragma unroll
    for (int mt = 0; mt < 4; ++mt) {
        const int ch = mt * 16 + col;
        const float a1 = g1[ch] * rsqrtf(v1[ch] + EPS_);
        const float c1 = fmaf(a1, b1[ch] - m1[ch], beta1[ch]);
#pragma unroll
        for (int j = 0; j < 4; ++j) {
            const int k = quad * 4 + j;
            float w;
            if (k < 9)        w = a1 * W1[k * 64 + ch];
            else if (k == 9)  w = c1;                      // bias slot (feat=1.0)
            else if (k == 10) w = a1 * W1[6 * 64 + ch];    // z_mean slot (feat=-zm)
            else              w = 0.0f;
            aw1[mt][j] = (_Float16)w;
        }
    }

    // ---- W2 (BN2-scale folded), k-rows permuted to match in-register h1 layout ----
    f16x8 bw2[2][4];
#pragma unroll
    for (int nt = 0; nt < 4; ++nt) {
        const int n0 = nt * 16 + col;
        const float a2 = g2[n0] * rsqrtf(v2[n0] + EPS_);
#pragma unroll
        for (int kt = 0; kt < 2; ++kt)
#pragma unroll
            for (int j = 0; j < 8; ++j) {
                const int c = 32 * kt + 16 * (j >> 2) + 4 * quad + (j & 3);
                bw2[kt][nt][j] = (_Float16)(a2 * W2[c * 64 + n0]);
            }
    }
    // lane's own output-channel bias (applied AFTER the row-max; max is shift-equivariant)
    const float c2own = fmaf(g2[lane] * rsqrtf(v2[lane] + EPS_),
                             b2[lane] - m2[lane], beta2[lane]);
    // r25: epilogue extract controls (hoisted)
    const int hshift = (quad & 1) << 4;     // lo/hi f16 half within the pair
    const bool hiPair = (quad >= 2);        // ph23 vs ph01

    // z reduction: sum valid z over 16-col groups (quads replicate), mean via rcp.
    // r26: no divide-guard — for n==0 the NaN is provably never consumed
    // (npu==0 skips body; res=NEG_ written directly).
    auto zreduce = [&](const float4& A, const float4& B, int n) -> float {
        float zs = (col < n) ? A.z : 0.0f;
        zs += (16 + col < n) ? B.z : 0.0f;
#pragma unroll
        for (int off = 1; off <= 8; off <<= 1) zs += __shfl_xor(zs, off, 64);
        return zs * fast_rcp((float)n);
    };

    const int nwaves = gridDim.x * WPB;
    int p = __builtin_amdgcn_readfirstlane(blockIdx.x * WPB + wave);
    if (p >= P) return;

    // ---- r22: pointer-bump addressing (constant strides, no per-iter p*K) ----
    const float4* pb   = (const float4*)pillars + (size_t)p * 32;
    const int*    npp  = npts_arr + p;
    const int*    cpp  = coords + 2 * (size_t)p;
    float*        outp = out + (size_t)p * 64 + lane;
    const size_t  pb_step  = (size_t)nwaves * 32;   // float4 units
    const size_t  out_step = (size_t)nwaves * 64;

    // ---- preamble: load + z for pillar 0 ----
    float4 ptA = pb[col];
    float4 ptB = pb[16 + col];
    int np = npp[0];                 // domain [0,32] by construction (r25)
    int cy = cpp[0], cx = cpp[1];
    float z_cur = zreduce(ptA, ptB, np);

    while (true) {
        const int pn = p + nwaves;
        const bool has_next = pn < P;
        float4 ptAn, ptBn; int npn = 0, cyn = 0, cxn = 0;
        if (has_next) {                       // wave-uniform; issue loads early
            const float4* pbn = pb + pb_step;
            ptAn = pbn[col];
            ptBn = pbn[16 + col];
            npn = npp[nwaves];
            cyn = cpp[2 * (size_t)nwaves];
            cxn = cpp[2 * (size_t)nwaves + 1];
        }

        const int npu = __builtin_amdgcn_readfirstlane(np);
        // r26: fma form — (c+0.5)*RES+MIN == fma(c, RES, MIN + RES/2)
        const float xc = fmaf((float)cx, RES_, XMIN_ + 0.5f * RES_);
        const float yc = fmaf((float)cy, RES_, YMIN_ + 0.5f * RES_);
        // r26: cab is per-PILLAR (depends only on z_mean) — hoisted from t-loop
        const f16x2 cab = pkrtz(-z_cur, 0.0f);     // quad2: -zm, 0

        // ================= pillar body (zero LDS) =================
        auto body = [&](auto MTC) -> float {
            constexpr int MT = decltype(MTC)::value;
            float hm4[4] = {NEG_, NEG_, NEG_, NEG_};   // r24 PIN: keep the init

#pragma unroll
            for (int t = 0; t < MT; ++t) {
                const float4 pt = (t == 0) ? ptA : ptB;

                // ---- feat^T B-frag: B[k=quad*4+j][n=point col] ----
                const float xo = pt.x - xc;
                const float yo = pt.y - yc;
                const f16x2 c01 = pkrtz(pt.x, pt.y);       // quad0: x,y
                const f16x2 c23 = pkrtz(pt.z, pt.w);       // quad0: z,r
                const f16x2 c45 = pkrtz(xo, yo);           // quad1: xo,yo
                const f16x2 c67 = pkrtz(pt.z, xo);         // quad1: z(slot6), xo
                const f16x2 c89 = pkrtz(yo, 1.0f);         // quad2: yo, bias-1
                const f16x2 z2  = (f16x2)(_Float16)0.f;
                F4u u;
                u.h[0] = (quad == 0) ? c01 : (quad == 1) ? c45 : (quad == 2) ? c89 : z2;
                u.h[1] = (quad == 0) ? c23 : (quad == 1) ? c67 : (quad == 2) ? cab : z2;
                const f16x4 bt = u.v;

                // ---- layer-1: 4 MFMAs, C=0 (bias+z in K-slots) ----
                f32x4 acc1[4];
                const f32x4 zz = {0.f, 0.f, 0.f, 0.f};
#pragma unroll
                for (int mt = 0; mt < 4; ++mt)
                    acc1[mt] = __builtin_amdgcn_mfma_f32_16x16x16f16(aw1[mt], bt, zz, 0, 0, 0);

                // ---- h1 relu + pack: layer-2 A-frags, pure in-lane ----
                f16x8 av2[2];
#pragma unroll
                for (int kt = 0; kt < 2; ++kt) {
                    F8u w;
                    w.h[0] = relu2(pkrtz(acc1[2 * kt][0],     acc1[2 * kt][1]));
                    w.h[1] = relu2(pkrtz(acc1[2 * kt][2],     acc1[2 * kt][3]));
                    w.h[2] = relu2(pkrtz(acc1[2 * kt + 1][0], acc1[2 * kt + 1][1]));
                    w.h[3] = relu2(pkrtz(acc1[2 * kt + 1][2], acc1[2 * kt + 1][3]));
                    av2[kt] = w.v;
                }

                // ---- row-mask as layer-2 C-init (free adds) ----
                f32x4 cm;
#pragma unroll
                for (int r = 0; r < 4; ++r)
                    cm[r] = (t * 16 + quad * 4 + r < np) ? 0.0f : NEG_;

                // ---- layer-2: stream per nt, fold into running max (max3) ----
#pragma unroll
                for (int nt = 0; nt < 4; ++nt) {
                    f32x4 acc = __builtin_amdgcn_mfma_f32_16x16x32_f16(av2[0], bw2[0][nt], cm, 0, 0, 0);
                    acc = __builtin_amdgcn_mfma_f32_16x16x32_f16(av2[1], bw2[1][nt], acc, 0, 0, 0);
                    hm4[nt] = max3f(hm4[nt], max3f(acc[0], acc[1], acc[2]), acc[3]);
                }
            }

            // ---- r25: packed-f16 cross-quad max (4 shfl + 4 pk_max) ----
            f16x2 ph01 = pkrtz(hm4[0], hm4[1]);
            f16x2 ph23 = pkrtz(hm4[2], hm4[3]);
#pragma unroll
            for (int off = 16; off <= 32; off <<= 1) {
                const int s01 = __shfl_xor(__builtin_bit_cast(int, ph01), off, 64);
                const int s23 = __shfl_xor(__builtin_bit_cast(int, ph23), off, 64);
                ph01 = pmax2(ph01, __builtin_bit_cast(f16x2, s01));
                ph23 = pmax2(ph23, __builtin_bit_cast(f16x2, s23));
            }
            // lane's channel = quad*16+col -> pair (quad>=2), half (quad&1)
            const int selu = hiPair ? __builtin_bit_cast(int, ph23)
                                    : __builtin_bit_cast(int, ph01);
            const _Float16 hown = __builtin_bit_cast(f16x2, selu >> hshift)[0];
            return fmaxf((float)hown + c2own, 0.0f);
        };

        float res;
        if (npu > 16)     res = body(std::integral_constant<int, 2>{});
        else if (npu > 0) res = body(std::integral_constant<int, 1>{});
        else              res = NEG_;
        *outp = res;

        if (!has_next) break;

        // ---- pipelined: z for NEXT pillar (shuffle chain overlaps MFMA drain) ----
        z_cur = zreduce(ptAn, ptBn, npn);

        p = pn; ptA = ptAn; ptB = ptBn; np = npn; cy = cyn; cx = cxn;
        pb += pb_step; npp += nwaves; cpp += 2 * (size_t)nwaves; outp += out_step;
    }
}

extern "C" void kernel_launch(void* const* d_in, const int* in_sizes, int n_in,
                              void* d_out, int out_size, void* d_ws, size_t ws_size,
                              hipStream_t stream) {
    const float* pillars = (const float*)d_in[0];
    const int*   coords  = (const int*)d_in[1];
    const int*   npts    = (const int*)d_in[2];
    const float* W1      = (const float*)d_in[3];
    const float* b1      = (const float*)d_in[4];
    const float* g1      = (const float*)d_in[5];
    const float* beta1   = (const float*)d_in[6];
    const float* m1      = (const float*)d_in[7];
    const float* v1      = (const float*)d_in[8];
    const float* W2      = (const float*)d_in[9];
    const float* b2      = (const float*)d_in[10];
    const float* g2      = (const float*)d_in[11];
    const float* beta2   = (const float*)d_in[12];
    const float* m2      = (const float*)d_in[13];
    const float* v2      = (const float*)d_in[14];
    float* out           = (float*)d_out;

    const int P = in_sizes[2];
    // 1024 blocks (4 blocks/CU), (256,4) — the measured optimum structure;
    // r22/r25/r26 = instruction-count diet on it.
    const int blocks = 1024;

    hipLaunchKernelGGL(pfn_kernel, dim3(blocks), dim3(256), 0, stream,
                       pillars, coords, npts, W1, b1, g1, beta1, m1, v1,
                       W2, b2, g2, beta2, m2, v2, out, P);
}

// Round 15
// 143.847 us; speedup vs baseline: 1.0011x; 1.0011x over previous
//
#include <hip/hip_runtime.h>
#include <type_traits>

#define RES_ 0.16f
#define XMIN_ -51.2f
#define YMIN_ -51.2f
#define EPS_ 1e-5f
#define NEG_ -1000000000.0f

#define WPB 4  // waves per block

typedef _Float16 f16x8 __attribute__((ext_vector_type(8)));
typedef _Float16 f16x4 __attribute__((ext_vector_type(4)));
typedef _Float16 f16x2 __attribute__((ext_vector_type(2)));
typedef float f32x4 __attribute__((ext_vector_type(4)));

union F8u { f16x8 v; f16x2 h[4]; };
union F4u { f16x4 v; f16x2 h[2]; };

// cvt_pkrtz returns __fp16x2 on this clang; launder to _Float16x2 (same bits)
static __device__ __forceinline__ f16x2 pkrtz(float a, float b) {
    return __builtin_bit_cast(f16x2, __builtin_amdgcn_cvt_pkrtz(a, b));
}

static __device__ __forceinline__ f16x2 pmax2(f16x2 a, f16x2 b) {
#if __has_builtin(__builtin_elementwise_max)
    return __builtin_elementwise_max(a, b);    // v_pk_max_f16
#else
    f16x2 r;
    r[0] = a[0] > b[0] ? a[0] : b[0];
    r[1] = a[1] > b[1] ? a[1] : b[1];
    return r;
#endif
}

static __device__ __forceinline__ f16x2 relu2(f16x2 x) {
    const f16x2 z2 = (f16x2)(_Float16)0.f;
    return pmax2(x, z2);
}

static __device__ __forceinline__ float fast_rcp(float x) {
#if __has_builtin(__builtin_amdgcn_rcpf)
    return __builtin_amdgcn_rcpf(x);   // v_rcp_f32, ~1ulp — fine at f16 downstream
#else
    return 1.0f / x;
#endif
}

// r22: single-instruction 3-input max (VOP3; gfx9+). clang does not reliably
// fuse nested fmaxf into v_max3_f32, so force it. Pure, no volatile.
static __device__ __forceinline__ float max3f(float a, float b, float c) {
    float d;
    asm("v_max3_f32 %0, %1, %2, %3" : "=v"(d) : "v"(a), "v"(b), "v"(c));
    return d;
}

// NOTE (r11): zero-LDS dataflow — layer-1 computed transposed (W1^T @ feat^T) so
// its MFMA C-output IS layer-2's A-operand under a W2 k-row permutation
// c(kt,quad,j)=32kt+16(j>>2)+4quad+(j&3). No LDS staging, no h1 round-trip.
// NOTE (FINAL ledger, per-dispatch us): r25 = 49.5 (BEST; this source) |
//  r26 micro-diet = 50.2 (flat — diet lever EXHAUSTED) | r22 = 53.0 (x2) |
//  r13 = 57.5 | r16/r23 = 59 | r19 bw2->LDS+5w = 60 | r15 grid2048 = 66 |
//  r21 X/Y skew = 72.5 | r18 pairing = 74 | r14 (256,8) spill = 252 |
//  r24 init-elision = FAILED (PIN: keep accumulator init).
// NOTE (model, FINAL): issue/latency equilibrium. Per-SIMD ~1250 cy/pillar ~=
//  4 waves x ~350 issued-cy/pillar — issue-port ~saturated via wave interleave.
//  No single-pipe roofline in counters (VALU 47%, MFMA 21%, HBM 14%), but all
//  levers measured: TLP neutral (r15/r19), ILP negative (r18/r21), reg-demand
//  neutral (r19), DS-elim negative (r16/r23), op-diet = the wins (r22 -7%,
//  r25 -6.6%) until exhausted (r26 flat). Untried: 32x32-MFMA dataflow
//  redesign (~10% modeled ceiling, multi-round, high regression risk).
// NOTE (attribution): max3f+pointer-bump -4.2us; packed-f16 epilogue -3.5us
//  (issue slots + serial shfl-chain halved 8->4). shfl beats DPP/permlane (x2).
//  absmax 47.3 tracks max3f reorder — benign, threshold 2e7.
// Tripwires: WRITE_SIZE==25000KB, VGPR<=60, LDS==0.
__global__ __launch_bounds__(256, 4) void pfn_kernel(
    const float* __restrict__ pillars,
    const int* __restrict__ coords,
    const int* __restrict__ npts_arr,
    const float* __restrict__ W1, const float* __restrict__ b1,
    const float* __restrict__ g1, const float* __restrict__ beta1,
    const float* __restrict__ m1, const float* __restrict__ v1,
    const float* __restrict__ W2, const float* __restrict__ b2,
    const float* __restrict__ g2, const float* __restrict__ beta2,
    const float* __restrict__ m2, const float* __restrict__ v2,
    float* __restrict__ out, int P)
{
    const int tid  = threadIdx.x;
    const int wave = tid >> 6;
    const int lane = tid & 63;
    const int quad = lane >> 4;
    const int col  = lane & 15;

    // ---- W1^T as layer-1 A-frags (K padded 9->16), BN1 scale+bias+z folded ----
    // A[m = mtile*16+col (channel)][k = quad*4+j (feat slot)]
    // slots: {x,y,z,r,xo,yo,z,xo,yo, 1.0(bias), -z_mean(w6 again), 0...}
    f16x4 aw1[4];
#pragma unroll
    for (int mt = 0; mt < 4; ++mt) {
        const int ch = mt * 16 + col;
        const float a1 = g1[ch] * rsqrtf(v1[ch] + EPS_);
        const float c1 = fmaf(a1, b1[ch] - m1[ch], beta1[ch]);
#pragma unroll
        for (int j = 0; j < 4; ++j) {
            const int k = quad * 4 + j;
            float w;
            if (k < 9)        w = a1 * W1[k * 64 + ch];
            else if (k == 9)  w = c1;                      // bias slot (feat=1.0)
            else if (k == 10) w = a1 * W1[6 * 64 + ch];    // z_mean slot (feat=-zm)
            else              w = 0.0f;
            aw1[mt][j] = (_Float16)w;
        }
    }

    // ---- W2 (BN2-scale folded), k-rows permuted to match in-register h1 layout ----
    f16x8 bw2[2][4];
#pragma unroll
    for (int nt = 0; nt < 4; ++nt) {
        const int n0 = nt * 16 + col;
        const float a2 = g2[n0] * rsqrtf(v2[n0] + EPS_);
#pragma unroll
        for (int kt = 0; kt < 2; ++kt)
#pragma unroll
            for (int j = 0; j < 8; ++j) {
                const int c = 32 * kt + 16 * (j >> 2) + 4 * quad + (j & 3);
                bw2[kt][nt][j] = (_Float16)(a2 * W2[c * 64 + n0]);
            }
    }
    // lane's own output-channel bias (applied AFTER the row-max; max is shift-equivariant)
    const float c2own = fmaf(g2[lane] * rsqrtf(v2[lane] + EPS_),
                             b2[lane] - m2[lane], beta2[lane]);
    // r25: epilogue extract controls (hoisted)
    const int hshift = (quad & 1) << 4;     // lo/hi f16 half within the pair
    const bool hiPair = (quad >= 2);        // ph23 vs ph01

    // z reduction: sum valid z over 16-col groups (quads replicate), mean via rcp
    auto zreduce = [&](const float4& A, const float4& B, int n) -> float {
        float zs = (col < n) ? A.z : 0.0f;
        zs += (16 + col < n) ? B.z : 0.0f;
#pragma unroll
        for (int off = 1; off <= 8; off <<= 1) zs += __shfl_xor(zs, off, 64);
        return zs * fast_rcp(fmaxf((float)n, 1.0f));
    };

    const int nwaves = gridDim.x * WPB;
    int p = __builtin_amdgcn_readfirstlane(blockIdx.x * WPB + wave);
    if (p >= P) return;

    // ---- r22: pointer-bump addressing (constant strides, no per-iter p*K) ----
    const float4* pb   = (const float4*)pillars + (size_t)p * 32;
    const int*    npp  = npts_arr + p;
    const int*    cpp  = coords + 2 * (size_t)p;
    float*        outp = out + (size_t)p * 64 + lane;
    const size_t  pb_step  = (size_t)nwaves * 32;   // float4 units
    const size_t  out_step = (size_t)nwaves * 64;

    // ---- preamble: load + z for pillar 0 ----
    float4 ptA = pb[col];
    float4 ptB = pb[16 + col];
    int np = npp[0];                 // domain [0,32] by construction
    int cy = cpp[0], cx = cpp[1];
    float z_cur = zreduce(ptA, ptB, np);

    while (true) {
        const int pn = p + nwaves;
        const bool has_next = pn < P;
        float4 ptAn, ptBn; int npn = 0, cyn = 0, cxn = 0;
        if (has_next) {                       // wave-uniform; issue loads early
            const float4* pbn = pb + pb_step;
            ptAn = pbn[col];
            ptBn = pbn[16 + col];
            npn = npp[nwaves];
            cyn = cpp[2 * (size_t)nwaves];
            cxn = cpp[2 * (size_t)nwaves + 1];
        }

        const int npu = __builtin_amdgcn_readfirstlane(np);
        const float xc = ((float)cx + 0.5f) * RES_ + XMIN_;
        const float yc = ((float)cy + 0.5f) * RES_ + YMIN_;
        const float z_mean = z_cur;

        // ================= pillar body (zero LDS) =================
        auto body = [&](auto MTC) -> float {
            constexpr int MT = decltype(MTC)::value;
            float hm4[4] = {NEG_, NEG_, NEG_, NEG_};   // r24 PIN: keep the init

#pragma unroll
            for (int t = 0; t < MT; ++t) {
                const float4 pt = (t == 0) ? ptA : ptB;

                // ---- feat^T B-frag: B[k=quad*4+j][n=point col] ----
                const float xo = pt.x - xc;
                const float yo = pt.y - yc;
                const f16x2 c01 = pkrtz(pt.x, pt.y);       // quad0: x,y
                const f16x2 c23 = pkrtz(pt.z, pt.w);       // quad0: z,r
                const f16x2 c45 = pkrtz(xo, yo);           // quad1: xo,yo
                const f16x2 c67 = pkrtz(pt.z, xo);         // quad1: z(slot6), xo
                const f16x2 c89 = pkrtz(yo, 1.0f);         // quad2: yo, bias-1
                const f16x2 cab = pkrtz(-z_mean, 0.0f);    // quad2: -zm, 0
                const f16x2 z2  = (f16x2)(_Float16)0.f;
                F4u u;
                u.h[0] = (quad == 0) ? c01 : (quad == 1) ? c45 : (quad == 2) ? c89 : z2;
                u.h[1] = (quad == 0) ? c23 : (quad == 1) ? c67 : (quad == 2) ? cab : z2;
                const f16x4 bt = u.v;

                // ---- layer-1: 4 MFMAs, C=0 (bias+z in K-slots) ----
                f32x4 acc1[4];
                const f32x4 zz = {0.f, 0.f, 0.f, 0.f};
#pragma unroll
                for (int mt = 0; mt < 4; ++mt)
                    acc1[mt] = __builtin_amdgcn_mfma_f32_16x16x16f16(aw1[mt], bt, zz, 0, 0, 0);

                // ---- h1 relu + pack: layer-2 A-frags, pure in-lane ----
                f16x8 av2[2];
#pragma unroll
                for (int kt = 0; kt < 2; ++kt) {
                    F8u w;
                    w.h[0] = relu2(pkrtz(acc1[2 * kt][0],     acc1[2 * kt][1]));
                    w.h[1] = relu2(pkrtz(acc1[2 * kt][2],     acc1[2 * kt][3]));
                    w.h[2] = relu2(pkrtz(acc1[2 * kt + 1][0], acc1[2 * kt + 1][1]));
                    w.h[3] = relu2(pkrtz(acc1[2 * kt + 1][2], acc1[2 * kt + 1][3]));
                    av2[kt] = w.v;
                }

                // ---- row-mask as layer-2 C-init (free adds) ----
                f32x4 cm;
#pragma unroll
                for (int r = 0; r < 4; ++r)
                    cm[r] = (t * 16 + quad * 4 + r < np) ? 0.0f : NEG_;

                // ---- layer-2: stream per nt, fold into running max (max3) ----
#pragma unroll
                for (int nt = 0; nt < 4; ++nt) {
                    f32x4 acc = __builtin_amdgcn_mfma_f32_16x16x32_f16(av2[0], bw2[0][nt], cm, 0, 0, 0);
                    acc = __builtin_amdgcn_mfma_f32_16x16x32_f16(av2[1], bw2[1][nt], acc, 0, 0, 0);
                    hm4[nt] = max3f(hm4[nt], max3f(acc[0], acc[1], acc[2]), acc[3]);
                }
            }

            // ---- r25: packed-f16 cross-quad max (4 shfl + 4 pk_max) ----
            // valid rows give finite O(100) values; NEG_ saturates to -inf in
            // f16 which is max-neutral. f16 rounding O(0.1) at output scale.
            f16x2 ph01 = pkrtz(hm4[0], hm4[1]);
            f16x2 ph23 = pkrtz(hm4[2], hm4[3]);
#pragma unroll
            for (int off = 16; off <= 32; off <<= 1) {
                const int s01 = __shfl_xor(__builtin_bit_cast(int, ph01), off, 64);
                const int s23 = __shfl_xor(__builtin_bit_cast(int, ph23), off, 64);
                ph01 = pmax2(ph01, __builtin_bit_cast(f16x2, s01));
                ph23 = pmax2(ph23, __builtin_bit_cast(f16x2, s23));
            }
            // lane's channel = quad*16+col -> pair (quad>=2), half (quad&1)
            const int selu = hiPair ? __builtin_bit_cast(int, ph23)
                                    : __builtin_bit_cast(int, ph01);
            const _Float16 hown = __builtin_bit_cast(f16x2, selu >> hshift)[0];
            return fmaxf((float)hown + c2own, 0.0f);
        };

        float res;
        if (npu > 16)     res = body(std::integral_constant<int, 2>{});
        else if (npu > 0) res = body(std::integral_constant<int, 1>{});
        else              res = NEG_;
        *outp = res;

        if (!has_next) break;

        // ---- pipelined: z for NEXT pillar (shuffle chain overlaps MFMA drain) ----
        z_cur = zreduce(ptAn, ptBn, npn);

        p = pn; ptA = ptAn; ptB = ptBn; np = npn; cy = cyn; cx = cxn;
        pb += pb_step; npp += nwaves; cpp += 2 * (size_t)nwaves; outp += out_step;
    }
}

extern "C" void kernel_launch(void* const* d_in, const int* in_sizes, int n_in,
                              void* d_out, int out_size, void* d_ws, size_t ws_size,
                              hipStream_t stream) {
    const float* pillars = (const float*)d_in[0];
    const int*   coords  = (const int*)d_in[1];
    const int*   npts    = (const int*)d_in[2];
    const float* W1      = (const float*)d_in[3];
    const float* b1      = (const float*)d_in[4];
    const float* g1      = (const float*)d_in[5];
    const float* beta1   = (const float*)d_in[6];
    const float* m1      = (const float*)d_in[7];
    const float* v1      = (const float*)d_in[8];
    const float* W2      = (const float*)d_in[9];
    const float* b2      = (const float*)d_in[10];
    const float* g2      = (const float*)d_in[11];
    const float* beta2   = (const float*)d_in[12];
    const float* m2      = (const float*)d_in[13];
    const float* v2      = (const float*)d_in[14];
    float* out           = (float*)d_out;

    const int P = in_sizes[2];
    // 1024 blocks (4 blocks/CU), (256,4) — the measured optimum structure;
    // r22/r25 = instruction-count diet on it. This source == r25 (best).
    const int blocks = 1024;

    hipLaunchKernelGGL(pfn_kernel, dim3(blocks), dim3(256), 0, stream,
                       pillars, coords, npts, W1, b1, g1, beta1, m1, v1,
                       W2, b2, g2, beta2, m2, v2, out, P);
}